// Round 13
// baseline (578.487 us; speedup 1.0000x reference)
//
#include <hip/hip_runtime.h>
#include <hip/hip_bf16.h>
#include <stdint.h>

typedef unsigned short ushort_t;
typedef __attribute__((ext_vector_type(8))) short short8;
typedef __attribute__((ext_vector_type(4))) float floatx4;

__device__ __forceinline__ float bf2f(unsigned short u){
  union { unsigned int i; float f; } v; v.i = ((unsigned int)u) << 16; return v.f;
}
__device__ __forceinline__ unsigned short f2bf(float f){
  union { float f; unsigned int i; } v; v.f = f;
  unsigned int r = v.i + 0x7FFFu + ((v.i >> 16) & 1u);
  return (unsigned short)(r >> 16);
}
__device__ __forceinline__ unsigned int pack2(unsigned short lo, unsigned short hi){
  return ((unsigned int)hi << 16) | (unsigned int)lo;
}

// ------------- edge_index storage detection (int32 words on this harness; probe kept for safety) -------------

__global__ __launch_bounds__(256) void k_detect(const unsigned int* __restrict__ w, int* __restrict__ flag){
  int t = threadIdx.x;
  unsigned int acc = 0;
  #pragma unroll
  for (int i=0;i<16;++i) acc |= w[2*(t*16+i)+1];
  #pragma unroll
  for (int o=32;o>=1;o>>=1) acc |= __shfl_xor(acc, o);
  if ((t&63)==0 && acc) atomicOr(flag, 1);
}

// ---------------- CSR build via 512-node bucket counting sort ----------------

__global__ __launch_bounds__(256) void k_bhist(const unsigned int* __restrict__ w, const int* __restrict__ mode,
                                               int* __restrict__ ghist, int E, int N){
  __shared__ int h[256];
  int t = threadIdx.x;
  h[t] = 0; __syncthreads();
  int m = *mode;
  int base = blockIdx.x*4096 + t;
  #pragma unroll
  for (int i=0;i<16;++i){
    int e = base + i*256;
    if (e < E){
      int d = m ? (int)w[(size_t)E + e] : (int)w[2*((size_t)E + e)];
      if ((unsigned)d < (unsigned)N) atomicAdd(&h[d>>9], 1);
    }
  }
  __syncthreads();
  if (h[t]) atomicAdd(&ghist[t], h[t]);
}

__global__ __launch_bounds__(256) void k_bscan(const int* __restrict__ ghist, int* __restrict__ bbase,
                                               int* __restrict__ gcur, int NB){
  __shared__ int sv[256];
  int t = threadIdx.x;
  int v = (t < NB) ? ghist[t] : 0;
  sv[t] = v; __syncthreads();
  for (int o=1;o<256;o<<=1){
    int xv = (t>=o)? sv[t-o] : 0;
    __syncthreads();
    sv[t] += xv;
    __syncthreads();
  }
  int excl = sv[t] - v;
  if (t < NB){ bbase[t] = excl; gcur[t] = excl; }
  if (t == NB-1) bbase[NB] = excl + v;
}

__global__ __launch_bounds__(256) void k_bin(const unsigned int* __restrict__ w, const int* __restrict__ mode,
                                             int* __restrict__ gcur, int2* __restrict__ pairs,
                                             int E, int N, int NB){
  __shared__ int h[256];
  __shared__ int cur[256];
  int t = threadIdx.x;
  h[t] = 0; __syncthreads();
  int m = *mode;
  int base = blockIdx.x*4096 + t;
  int d[16], s[16];
  #pragma unroll
  for (int i=0;i<16;++i){
    int e = base + i*256;
    d[i] = -1; s[i] = 0;
    if (e < E){
      if (m){ s[i] = (int)w[e];           d[i] = (int)w[(size_t)E + e]; }
      else  { s[i] = (int)w[2*(size_t)e]; d[i] = (int)w[2*((size_t)E + e)]; }
      if ((unsigned)d[i] >= (unsigned)N || (unsigned)s[i] >= (unsigned)N) d[i] = -1;
    }
  }
  #pragma unroll
  for (int i=0;i<16;++i)
    if (d[i] >= 0) atomicAdd(&h[d[i]>>9], 1);
  __syncthreads();
  if (t < NB && h[t]) cur[t] = atomicAdd(&gcur[t], h[t]);
  __syncthreads();
  #pragma unroll
  for (int i=0;i<16;++i){
    if (d[i] >= 0){
      int p = atomicAdd(&cur[d[i]>>9], 1);
      pairs[p] = make_int2(d[i], s[i]);
    }
  }
}

__global__ __launch_bounds__(256) void k_bcsr(const int2* __restrict__ pairs, const int* __restrict__ bbase,
                                              int* __restrict__ offs, int* __restrict__ csr, int N, int NB){
  __shared__ int cnt[512];
  __shared__ int wsum[4];
  int b = blockIdx.x, t = threadIdx.x, lane = t&63, wv = t>>6;
  int lo = bbase[b], hi = bbase[b+1];
  int node0 = b << 9;
  cnt[t] = 0; cnt[t+256] = 0;
  __syncthreads();
  for (int i = lo+t; i < hi; i += 256){
    int2 p = pairs[i];
    atomicAdd(&cnt[p.x - node0], 1);
  }
  __syncthreads();
  int v0 = cnt[2*t], v1 = cnt[2*t+1], tot = v0+v1;
  int s = tot;
  #pragma unroll
  for (int o=1;o<64;o<<=1){ int xv = __shfl_up(s,o); if (lane>=o) s += xv; }
  if (lane==63) wsum[wv] = s;
  __syncthreads();
  int basev = 0;
  for (int j=0;j<wv;++j) basev += wsum[j];
  int excl = basev + s - tot;
  int e0 = lo + excl, e1 = lo + excl + v0;
  cnt[2*t] = e0; cnt[2*t+1] = e1;
  int n0 = node0 + 2*t, n1 = node0 + 2*t + 1;
  if (n0 < N) offs[n0] = e0;
  if (n1 < N) offs[n1] = e1;
  if (b == NB-1 && t == 255) offs[N] = hi;
  __syncthreads();
  for (int i = lo+t; i < hi; i += 256){
    int2 p = pairs[i];
    int pos = atomicAdd(&cnt[p.x - node0], 1);
    csr[pos] = p.y;
  }
}

// ------------- weight permutation: f32 row-major -> bf16 MFMA-B layout -------------

__global__ __launch_bounds__(256) void k_perm(const float* W1a, const float* W1b, const float* W2a,
                                              const float* W2b, const float* W3a, const float* W3b,
                                              const float* Wfc, ushort_t* out){
  int id = blockIdx.x*256 + threadIdx.x;
  const float* src; int K, M, base, local;
  if      (id <  8192){ src=W1a; K=64;  M=128; base=0;     local=id; }
  else if (id < 24576){ src=W1b; K=128; M=128; base=8192;  local=id-8192; }
  else if (id < 40960){ src=W2a; K=128; M=128; base=24576; local=id-24576; }
  else if (id < 57344){ src=W2b; K=128; M=128; base=40960; local=id-40960; }
  else if (id < 65536){ src=W3a; K=128; M=64;  base=57344; local=id-57344; }
  else if (id < 69632){ src=W3b; K=64;  M=64;  base=65536; local=id-65536; }
  else if (id < 70656){ src=Wfc; K=64;  M=16;  base=69632; local=id-69632; }
  else return;
  int k = local / M, nn = local - k*M;
  float val;
  if (src == Wfc) val = (nn<8) ? Wfc[k*8+nn] : 0.0f;
  else            val = src[k*M+nn];
  int idx = (((nn>>4)*(K/32) + (k>>5))*4 + ((k>>3)&3))*128 + (nn&15)*8 + (k&7);
  out[base+idx] = f2bf(val);
}

// ------------- x -> bf16 pre-conversion -------------

__global__ __launch_bounds__(256) void k_tobf(const float2* __restrict__ xin, unsigned int* __restrict__ xb, int total2){
  int i = blockIdx.x*256 + threadIdx.x;
  if (i < total2){
    float2 v = xin[i];
    xb[i] = pack2(f2bf(v.x), f2bf(v.y));
  }
}

// ---------------- fused gather + MFMA MLP, single wave-private LDS buffer ----------------
// ALL LDS accesses are wave-private (wave w touches rows [16w,16w+16) only) and the three
// roles (hA gather staging -> sC1 hidden acts -> sX3 final acts) have nested lifetimes
// within each wave (in-order DS pipe). So: ONE 17.4 KB buffer, NO barriers.
// 17.4 KB -> 8 blocks/CU (round 12's 34.8 KB gave 33% occupancy = the regression).

template<int F, int M1, int M2, bool LAST>
__global__ __launch_bounds__(256)
void k_gmlp(const uint2* __restrict__ xr, const int* __restrict__ offs,
            const int* __restrict__ csr, const float* __restrict__ epsp,
            const ushort_t* __restrict__ wp1, const float* __restrict__ b1,
            const ushort_t* __restrict__ wp2, const float* __restrict__ b2,
            ushort_t* __restrict__ xout,      // !LAST: bf16 next-layer x
            float* __restrict__ embp,         // LAST: f32 emb
            const ushort_t* __restrict__ wpfc, const float* __restrict__ bfc,
            float* __restrict__ outp, int n)
{
  constexpr int NT1 = M1/16, NT2 = M2/16, KC1 = F/32, KC2 = M1/32;
  constexpr int G2 = F/4;        // uint2 lanes per row: 32 (F=128), 16 (F=64)
  constexpr int NG = 64/G2;      // edge groups per wave: 2 or 4
  __shared__ short U[4*16*136];  // wave w owns U[w*16*136 .. (w+1)*16*136)
  int tid = threadIdx.x, lane = tid&63, w = tid>>6;
  int m16 = lane&15, quad = lane>>4;
  int row0 = blockIdx.x*64 + w*16;
  short* Uw = &U[w*16*136];

  // ---- phase 1: gather this wave's 16 rows into Uw (hA role) ----
  {
    int grp = lane / G2, f = lane % G2;
    float e1s = 1.0f + epsp[0];
#define ACC4(v) { a0 += bf2f((ushort_t)((v).x & 0xffffu)); a1 += bf2f((ushort_t)((v).x >> 16)); \
                  a2 += bf2f((ushort_t)((v).y & 0xffffu)); a3 += bf2f((ushort_t)((v).y >> 16)); }
    for (int i=0;i<16;++i){
      int node = row0 + i;
      float a0=0.f, a1=0.f, a2=0.f, a3=0.f;
      if (node < n){
        if (grp == 0){
          uint2 sv = xr[(size_t)node*G2 + f];
          a0 = e1s*bf2f((ushort_t)(sv.x & 0xffffu)); a1 = e1s*bf2f((ushort_t)(sv.x >> 16));
          a2 = e1s*bf2f((ushort_t)(sv.y & 0xffffu)); a3 = e1s*bf2f((ushort_t)(sv.y >> 16));
        }
        int u0 = offs[node], u1 = offs[node+1];
        int u = u0;
        for (; u + 4*NG-1 < u1; u += 4*NG){
          int s0 = csr[u        + grp];
          int s1 = csr[u +   NG + grp];
          int s2 = csr[u + 2*NG + grp];
          int s3 = csr[u + 3*NG + grp];
          uint2 v0 = xr[(size_t)s0*G2 + f];
          uint2 v1 = xr[(size_t)s1*G2 + f];
          uint2 v2 = xr[(size_t)s2*G2 + f];
          uint2 v3 = xr[(size_t)s3*G2 + f];
          ACC4(v0) ACC4(v1) ACC4(v2) ACC4(v3)
        }
        for (; u + NG-1 < u1; u += NG){
          int s = csr[u + grp];
          uint2 v = xr[(size_t)s*G2 + f];
          ACC4(v)
        }
        if (u + grp < u1){
          int s = csr[u + grp];
          uint2 v = xr[(size_t)s*G2 + f];
          ACC4(v)
        }
      }
      #pragma unroll
      for (int off=G2; off<64; off<<=1){
        a0 += __shfl_xor(a0, off);
        a1 += __shfl_xor(a1, off);
        a2 += __shfl_xor(a2, off);
        a3 += __shfl_xor(a3, off);
      }
      if (grp == 0){
        uint2 o2;
        o2.x = pack2(f2bf(a0), f2bf(a1));
        o2.y = pack2(f2bf(a2), f2bf(a3));
        *(uint2*)&Uw[i*136 + f*4] = o2;
      }
    }
#undef ACC4
  }

  // ---- phase 2: mm1 (reads hA role rows, then overwrites with sC1 role — wave-in-order) ----
  floatx4 acc[NT1];
  #pragma unroll
  for (int i=0;i<NT1;++i) acc[i] = (floatx4){0.f,0.f,0.f,0.f};
  #pragma unroll
  for (int kc=0; kc<KC1; ++kc){
    short8 a = *(const short8*)&Uw[m16*136 + kc*32 + quad*8];
    #pragma unroll
    for (int nt=0; nt<NT1; ++nt){
      short8 b = *(const short8*)(wp1 + (size_t)((nt*KC1+kc)*64 + lane)*8);
      acc[nt] = __builtin_amdgcn_mfma_f32_16x16x32_bf16(a, b, acc[nt], 0, 0, 0);
    }
  }
  #pragma unroll
  for (int nt=0; nt<NT1; ++nt){
    int c = nt*16 + m16;
    float bias = b1[c];
    #pragma unroll
    for (int r=0;r<4;++r){
      float v = fmaxf(acc[nt][r] + bias, 0.f);
      int mm = quad*4 + r;
      Uw[(c>>3)*136 + mm*8 + (c&7)] = (short)f2bf(v);
    }
  }

  // ---- mm2 (reads sC1 role, epilogue writes global / sX3 role) ----
  floatx4 acc2[NT2];
  #pragma unroll
  for (int i=0;i<NT2;++i) acc2[i] = (floatx4){0.f,0.f,0.f,0.f};
  #pragma unroll
  for (int kc=0; kc<KC2; ++kc){
    short8 a = *(const short8*)&Uw[(kc*4 + quad)*136 + m16*8];
    #pragma unroll
    for (int nt=0; nt<NT2; ++nt){
      short8 b = *(const short8*)(wp2 + (size_t)((nt*KC2+kc)*64 + lane)*8);
      acc2[nt] = __builtin_amdgcn_mfma_f32_16x16x32_bf16(a, b, acc2[nt], 0, 0, 0);
    }
  }
  #pragma unroll
  for (int nt=0; nt<NT2; ++nt){
    int c = nt*16 + m16;
    float bias = b2[c];
    #pragma unroll
    for (int r=0;r<4;++r){
      float v = fmaxf(acc2[nt][r] + bias, 0.f);
      int mm = quad*4 + r;
      int row = row0 + mm;
      if constexpr (!LAST){
        if (row < n) xout[(size_t)row*M2 + c] = f2bf(v);
      } else {
        if (row < n) embp[(size_t)row*64 + c] = v;                // f32 emb
        Uw[(c>>3)*136 + mm*8 + (c&7)] = (short)f2bf(v);           // sX3 role
      }
    }
  }

  if constexpr (LAST){
    floatx4 accf = (floatx4){0.f,0.f,0.f,0.f};
    #pragma unroll
    for (int kc=0; kc<2; ++kc){
      short8 a = *(const short8*)&Uw[(kc*4 + quad)*136 + m16*8];
      short8 b = *(const short8*)(wpfc + (size_t)(kc*64 + lane)*8);
      accf = __builtin_amdgcn_mfma_f32_16x16x32_bf16(a, b, accf, 0, 0, 0);
    }
    if (m16 < 8){
      float bias = bfc[m16];
      #pragma unroll
      for (int r=0;r<4;++r){
        int row = row0 + quad*4 + r;
        if (row < n) outp[(size_t)row*8 + m16] = accf[r] + bias;  // f32 out
      }
    }
  }
}

// ---------------- launcher ----------------

extern "C" void kernel_launch(void* const* d_in, const int* in_sizes, int n_in,
                              void* d_out, int out_size, void* d_ws, size_t ws_size,
                              hipStream_t stream)
{
  const int N = in_sizes[0] / 64;
  const int E = in_sizes[1] / 2;
  const int NB = (N + 511) / 512;
  const float*        x    = (const float*)d_in[0];
  const unsigned int* ew   = (const unsigned int*)d_in[1];
  const float* eps1 = (const float*)d_in[2];
  const float* eps2 = (const float*)d_in[3];
  const float* eps3 = (const float*)d_in[4];
  const float* W1a  = (const float*)d_in[5];
  const float* b1a  = (const float*)d_in[6];
  const float* W1b  = (const float*)d_in[7];
  const float* b1b  = (const float*)d_in[8];
  const float* W2a  = (const float*)d_in[9];
  const float* b2a  = (const float*)d_in[10];
  const float* W2b  = (const float*)d_in[11];
  const float* b2b  = (const float*)d_in[12];
  const float* W3a  = (const float*)d_in[13];
  const float* b3a  = (const float*)d_in[14];
  const float* W3b  = (const float*)d_in[15];
  const float* b3b  = (const float*)d_in[16];
  const float* Wfc  = (const float*)d_in[17];
  const float* bfc  = (const float*)d_in[18];

  float* outp = (float*)d_out;                 // f32 output (verified round 6)
  float* emb  = outp + (size_t)N*8;

  const int Npad = ((N + 63)/64)*64;

  char* ws = (char*)d_ws;
  size_t o = 0;
  auto alloc = [&](size_t bytes)->char* {
    char* p = ws + o;
    o = (o + bytes + 255) & ~(size_t)255;
    return p;
  };
  int*      mode  = (int*)alloc(4);
  int*      ghist = (int*)alloc(256*4);
  int*      bbase = (int*)alloc(257*4);
  int*      gcur  = (int*)alloc(256*4);
  int*      offs  = (int*)alloc((size_t)(N+1)*4);
  int2*     pairs = (int2*)alloc((size_t)E*8);
  int*      csr   = (int*)alloc((size_t)E*4);
  ushort_t* wperm = (ushort_t*)alloc(70656ull*2);
  ushort_t* xb    = (ushort_t*)alloc((size_t)Npad*64*2);    // bf16 copy of x
  ushort_t* x1    = (ushort_t*)alloc((size_t)Npad*128*2);   // layer1 out
  ushort_t* x2    = (ushort_t*)alloc((size_t)Npad*128*2);   // layer2 out

  hipMemsetAsync(mode, 0, 4, stream);
  hipMemsetAsync(ghist, 0, 256*4, stream);
  k_detect<<<1, 256, 0, stream>>>(ew, mode);
  const int nbB = (E + 4095)/4096;
  k_bhist<<<nbB, 256, 0, stream>>>(ew, mode, ghist, E, N);
  k_bscan<<<1, 256, 0, stream>>>(ghist, bbase, gcur, NB);
  k_bin<<<nbB, 256, 0, stream>>>(ew, mode, gcur, pairs, E, N, NB);
  k_bcsr<<<NB, 256, 0, stream>>>(pairs, bbase, offs, csr, N, NB);
  k_perm<<<(70656+255)/256, 256, 0, stream>>>(W1a, W1b, W2a, W2b, W3a, W3b, Wfc, wperm);
  k_tobf<<<(N*32+255)/256, 256, 0, stream>>>((const float2*)x, (unsigned int*)xb, N*32);

  const int gblk = (N + 63)/64;
  // layer 1: gather(F=64) + MLP 64->128->128
  k_gmlp<64,128,128,false><<<gblk, 256, 0, stream>>>((const uint2*)xb, offs, csr, eps1,
                                                     wperm+0, b1a, wperm+8192, b1b,
                                                     x1, nullptr, nullptr, nullptr, nullptr, N);
  // layer 2: gather(F=128) + MLP 128->128->128
  k_gmlp<128,128,128,false><<<gblk, 256, 0, stream>>>((const uint2*)x1, offs, csr, eps2,
                                                      wperm+24576, b2a, wperm+40960, b2b,
                                                      x2, nullptr, nullptr, nullptr, nullptr, N);
  // layer 3: gather(F=128) + MLP 128->64->64 + emb + FC
  k_gmlp<128,64,64,true><<<gblk, 256, 0, stream>>>((const uint2*)x2, offs, csr, eps3,
                                                   wperm+57344, b3a, wperm+65536, b3b,
                                                   nullptr, emb, wperm+69632, bfc, outp, N);
}

// Round 14
// 416.212 us; speedup vs baseline: 1.3899x; 1.3899x over previous
//
#include <hip/hip_runtime.h>
#include <hip/hip_bf16.h>
#include <stdint.h>

typedef unsigned short ushort_t;
typedef __attribute__((ext_vector_type(8))) short short8;
typedef __attribute__((ext_vector_type(4))) float floatx4;

__device__ __forceinline__ float bf2f(unsigned short u){
  union { unsigned int i; float f; } v; v.i = ((unsigned int)u) << 16; return v.f;
}
__device__ __forceinline__ unsigned short f2bf(float f){
  union { float f; unsigned int i; } v; v.f = f;
  unsigned int r = v.i + 0x7FFFu + ((v.i >> 16) & 1u);
  return (unsigned short)(r >> 16);
}
__device__ __forceinline__ unsigned int pack2(unsigned short lo, unsigned short hi){
  return ((unsigned int)hi << 16) | (unsigned int)lo;
}
// 2-op bf16-pair unpack: lo half = v<<16, hi half = v & 0xffff0000
__device__ __forceinline__ float bflo(unsigned int v){
  union { unsigned int u; float f; } c; c.u = v << 16; return c.f;
}
__device__ __forceinline__ float bfhi(unsigned int v){
  union { unsigned int u; float f; } c; c.u = v & 0xffff0000u; return c.f;
}

// ---------------- prep kernel: [bucket histogram | x->bf16 | weight perm] by block range ----------------
// Per-block int64/int32 storage detect: OR 4096 odd words of this block's span
// (int64 storage => all-zero high halves; P(false positive | int32) ~ (1e-5)^2560 ~ 0).

__global__ __launch_bounds__(256)
void k_prep(const unsigned int* __restrict__ w, int* __restrict__ ghist, int E, int N, int nbB,
            const float2* __restrict__ xin, unsigned int* __restrict__ xb, int total2, int tobfB,
            const float* __restrict__ W1a, const float* __restrict__ W1b, const float* __restrict__ W2a,
            const float* __restrict__ W2b, const float* __restrict__ W3a, const float* __restrict__ W3b,
            const float* __restrict__ Wfc, ushort_t* __restrict__ wout)
{
  int b = blockIdx.x, t = threadIdx.x;
  if (b < nbB){
    __shared__ int h[256];
    __shared__ unsigned int dred[4];
    h[t] = 0;
    int base = b*4096 + t;
    unsigned int acc = 0;
    #pragma unroll
    for (int i=0;i<16;++i){
      int e = base + i*256;
      if (e < E) acc |= w[2*e+1];
    }
    #pragma unroll
    for (int o=32;o>=1;o>>=1) acc |= __shfl_xor(acc, o);
    if ((t&63)==0) dred[t>>6] = acc;
    __syncthreads();
    int m = (dred[0]|dred[1]|dred[2]|dred[3]) != 0;   // 1 => int32 words
    #pragma unroll
    for (int i=0;i<16;++i){
      int e = base + i*256;
      if (e < E){
        int d = m ? (int)w[(size_t)E + e] : (int)w[2*((size_t)E + e)];
        if ((unsigned)d < (unsigned)N) atomicAdd(&h[d>>9], 1);
      }
    }
    __syncthreads();
    if (h[t]) atomicAdd(&ghist[t], h[t]);
  } else if (b < nbB + tobfB){
    int i = (b - nbB)*256 + t;
    if (i < total2){
      float2 v = xin[i];
      xb[i] = pack2(f2bf(v.x), f2bf(v.y));
    }
  } else {
    int id = (b - nbB - tobfB)*256 + t;
    const float* src; int K, M, base2, local;
    if      (id <  8192){ src=W1a; K=64;  M=128; base2=0;     local=id; }
    else if (id < 24576){ src=W1b; K=128; M=128; base2=8192;  local=id-8192; }
    else if (id < 40960){ src=W2a; K=128; M=128; base2=24576; local=id-24576; }
    else if (id < 57344){ src=W2b; K=128; M=128; base2=40960; local=id-40960; }
    else if (id < 65536){ src=W3a; K=128; M=64;  base2=57344; local=id-57344; }
    else if (id < 69632){ src=W3b; K=64;  M=64;  base2=65536; local=id-65536; }
    else if (id < 70656){ src=Wfc; K=64;  M=16;  base2=69632; local=id-69632; }
    else return;
    int k = local / M, nn = local - k*M;
    float val;
    if (src == Wfc) val = (nn<8) ? Wfc[k*8+nn] : 0.0f;
    else            val = src[k*M+nn];
    int idx = (((nn>>4)*(K/32) + (k>>5))*4 + ((k>>3)&3))*128 + (nn&15)*8 + (k&7);
    wout[base2+idx] = f2bf(val);
  }
}

// ---------------- CSR build via 512-node bucket counting sort ----------------

__global__ __launch_bounds__(256) void k_bscan(const int* __restrict__ ghist, int* __restrict__ bbase,
                                               int* __restrict__ gcur, int NB){
  __shared__ int sv[256];
  int t = threadIdx.x;
  int v = (t < NB) ? ghist[t] : 0;
  sv[t] = v; __syncthreads();
  for (int o=1;o<256;o<<=1){
    int xv = (t>=o)? sv[t-o] : 0;
    __syncthreads();
    sv[t] += xv;
    __syncthreads();
  }
  int excl = sv[t] - v;
  if (t < NB){ bbase[t] = excl; gcur[t] = excl; }
  if (t == NB-1) bbase[NB] = excl + v;
}

__global__ __launch_bounds__(256) void k_bin(const unsigned int* __restrict__ w,
                                             int* __restrict__ gcur, int2* __restrict__ pairs,
                                             int E, int N, int NB){
  __shared__ int h[256];
  __shared__ int cur[256];
  __shared__ unsigned int dred[4];
  int t = threadIdx.x;
  h[t] = 0;
  int base = blockIdx.x*4096 + t;
  unsigned int acc = 0;
  #pragma unroll
  for (int i=0;i<16;++i){
    int e = base + i*256;
    if (e < E) acc |= w[2*e+1];
  }
  #pragma unroll
  for (int o=32;o>=1;o>>=1) acc |= __shfl_xor(acc, o);
  if ((t&63)==0) dred[t>>6] = acc;
  __syncthreads();
  int m = (dred[0]|dred[1]|dred[2]|dred[3]) != 0;
  int d[16], s[16];
  #pragma unroll
  for (int i=0;i<16;++i){
    int e = base + i*256;
    d[i] = -1; s[i] = 0;
    if (e < E){
      if (m){ s[i] = (int)w[e];           d[i] = (int)w[(size_t)E + e]; }
      else  { s[i] = (int)w[2*(size_t)e]; d[i] = (int)w[2*((size_t)E + e)]; }
      if ((unsigned)d[i] >= (unsigned)N || (unsigned)s[i] >= (unsigned)N) d[i] = -1;
    }
  }
  #pragma unroll
  for (int i=0;i<16;++i)
    if (d[i] >= 0) atomicAdd(&h[d[i]>>9], 1);
  __syncthreads();
  if (t < NB && h[t]) cur[t] = atomicAdd(&gcur[t], h[t]);
  __syncthreads();
  #pragma unroll
  for (int i=0;i<16;++i){
    if (d[i] >= 0){
      int p = atomicAdd(&cur[d[i]>>9], 1);
      pairs[p] = make_int2(d[i], s[i]);
    }
  }
}

__global__ __launch_bounds__(256) void k_bcsr(const int2* __restrict__ pairs, const int* __restrict__ bbase,
                                              int* __restrict__ offs, int* __restrict__ csr, int N, int NB){
  __shared__ int cnt[512];
  __shared__ int wsum[4];
  int b = blockIdx.x, t = threadIdx.x, lane = t&63, wv = t>>6;
  int lo = bbase[b], hi = bbase[b+1];
  int node0 = b << 9;
  cnt[t] = 0; cnt[t+256] = 0;
  __syncthreads();
  for (int i = lo+t; i < hi; i += 256){
    int2 p = pairs[i];
    atomicAdd(&cnt[p.x - node0], 1);
  }
  __syncthreads();
  int v0 = cnt[2*t], v1 = cnt[2*t+1], tot = v0+v1;
  int s = tot;
  #pragma unroll
  for (int o=1;o<64;o<<=1){ int xv = __shfl_up(s,o); if (lane>=o) s += xv; }
  if (lane==63) wsum[wv] = s;
  __syncthreads();
  int basev = 0;
  for (int j=0;j<wv;++j) basev += wsum[j];
  int excl = basev + s - tot;
  int e0 = lo + excl, e1 = lo + excl + v0;
  cnt[2*t] = e0; cnt[2*t+1] = e1;
  int n0 = node0 + 2*t, n1 = node0 + 2*t + 1;
  if (n0 < N) offs[n0] = e0;
  if (n1 < N) offs[n1] = e1;
  if (b == NB-1 && t == 255) offs[N] = hi;
  __syncthreads();
  for (int i = lo+t; i < hi; i += 256){
    int2 p = pairs[i];
    int pos = atomicAdd(&cnt[p.x - node0], 1);
    csr[pos] = p.y;
  }
}

// ------------- gather (both F): half-row-pair scheme, 8 loads in flight per half -------------

template<int F>
__global__ __launch_bounds__(256) void k_gatherx(const uint2* __restrict__ xr, const int* __restrict__ offs,
                                                 const int* __restrict__ csr, const float* __restrict__ epsp,
                                                 uint2* __restrict__ hr, int n){
  constexpr int G = F/4;           // lanes per row (uint2 each): 32 (F=128), 16 (F=64)
  constexpr int NPW = 64/(2*G);    // nodes per wave: 1 (F=128), 2 (F=64)
  int gt = blockIdx.x*256 + threadIdx.x;
  int wv = gt >> 6, lane = gt & 63;
  int grp  = lane / (2*G);
  int half = (lane / G) & 1;
  int f    = lane % G;
  int node = wv*NPW + grp;
  if (node >= n) return;
  const size_t row = (size_t)node*G;
  uint2 sv = xr[row + f];
  float e1s = 1.0f + epsp[0];
  float a0, a1, a2, a3;
  if (half == 0){
    a0 = e1s*bflo(sv.x); a1 = e1s*bfhi(sv.x);
    a2 = e1s*bflo(sv.y); a3 = e1s*bfhi(sv.y);
  } else { a0 = a1 = a2 = a3 = 0.f; }
  int u0 = offs[node], u1 = offs[node+1];
  int u = u0;
#define ACC4(v) { a0 += bflo((v).x); a1 += bfhi((v).x); a2 += bflo((v).y); a3 += bfhi((v).y); }
  for (; u+15 < u1; u += 16){
    int s0 = csr[u    + half], s1 = csr[u+2  + half], s2 = csr[u+4  + half], s3 = csr[u+6  + half];
    int s4 = csr[u+8  + half], s5 = csr[u+10 + half], s6 = csr[u+12 + half], s7 = csr[u+14 + half];
    uint2 v0 = xr[(size_t)s0*G + f];
    uint2 v1 = xr[(size_t)s1*G + f];
    uint2 v2 = xr[(size_t)s2*G + f];
    uint2 v3 = xr[(size_t)s3*G + f];
    uint2 v4 = xr[(size_t)s4*G + f];
    uint2 v5 = xr[(size_t)s5*G + f];
    uint2 v6 = xr[(size_t)s6*G + f];
    uint2 v7 = xr[(size_t)s7*G + f];
    ACC4(v0) ACC4(v1) ACC4(v2) ACC4(v3) ACC4(v4) ACC4(v5) ACC4(v6) ACC4(v7)
  }
  for (; u+7 < u1; u += 8){
    int s0 = csr[u + half], s1 = csr[u+2 + half], s2 = csr[u+4 + half], s3 = csr[u+6 + half];
    uint2 v0 = xr[(size_t)s0*G + f];
    uint2 v1 = xr[(size_t)s1*G + f];
    uint2 v2 = xr[(size_t)s2*G + f];
    uint2 v3 = xr[(size_t)s3*G + f];
    ACC4(v0) ACC4(v1) ACC4(v2) ACC4(v3)
  }
  for (; u+1 < u1; u += 2){
    int s = csr[u + half];
    uint2 v = xr[(size_t)s*G + f];
    ACC4(v)
  }
  if (u < u1 && half == 0){
    int s = csr[u];
    uint2 v = xr[(size_t)s*G + f];
    ACC4(v)
  }
#undef ACC4
  a0 += __shfl_xor(a0, G);
  a1 += __shfl_xor(a1, G);
  a2 += __shfl_xor(a2, G);
  a3 += __shfl_xor(a3, G);
  if (half == 0){
    uint2 o2;
    o2.x = pack2(f2bf(a0), f2bf(a1));
    o2.y = pack2(f2bf(a2), f2bf(a3));
    hr[row + f] = o2;
  }
}

// ---------------- fused MFMA MLP: x_next = relu(relu(h@Wa+ba)@Wb+bb); LAST adds emb(f32)+FC(f32) ----------------

template<int F, int M1, int M2, bool LAST>
__global__ __launch_bounds__(256)
void k_mlp(const ushort_t* __restrict__ h,
           const ushort_t* __restrict__ wp1, const float* __restrict__ b1,
           const ushort_t* __restrict__ wp2, const float* __restrict__ b2,
           ushort_t* __restrict__ xout,      // !LAST: bf16 next-layer x
           float* __restrict__ embp,         // LAST: f32 emb
           const ushort_t* __restrict__ wpfc, const float* __restrict__ bfc,
           float* __restrict__ outp, int n)
{
  constexpr int NT1 = M1/16, NT2 = M2/16, KC1 = F/32, KC2 = M1/32;
  __shared__ short sC1[4*(M1/8)*136];
  __shared__ short sX3[LAST ? (4*8*136) : 1];
  int tid = threadIdx.x, lane = tid&63, w = tid>>6;
  int m16 = lane&15, quad = lane>>4;
  int row0 = blockIdx.x*64 + w*16;
  size_t arow = (size_t)(row0 + m16);

  floatx4 acc[NT1];
  #pragma unroll
  for (int i=0;i<NT1;++i) acc[i] = (floatx4){0.f,0.f,0.f,0.f};
  #pragma unroll
  for (int kc=0; kc<KC1; ++kc){
    short8 a = *(const short8*)(h + arow*F + kc*32 + quad*8);
    #pragma unroll
    for (int nt=0; nt<NT1; ++nt){
      short8 b = *(const short8*)(wp1 + (size_t)((nt*KC1+kc)*64 + lane)*8);
      acc[nt] = __builtin_amdgcn_mfma_f32_16x16x32_bf16(a, b, acc[nt], 0, 0, 0);
    }
  }
  #pragma unroll
  for (int nt=0; nt<NT1; ++nt){
    int c = nt*16 + m16;
    float bias = b1[c];
    #pragma unroll
    for (int r=0;r<4;++r){
      float v = fmaxf(acc[nt][r] + bias, 0.f);
      int mm = quad*4 + r;
      sC1[(w*(M1/8) + (c>>3))*136 + mm*8 + (c&7)] = (short)f2bf(v);
    }
  }
  __syncthreads();

  floatx4 acc2[NT2];
  #pragma unroll
  for (int i=0;i<NT2;++i) acc2[i] = (floatx4){0.f,0.f,0.f,0.f};
  #pragma unroll
  for (int kc=0; kc<KC2; ++kc){
    short8 a = *(const short8*)&sC1[(w*(M1/8) + kc*4 + quad)*136 + m16*8];
    #pragma unroll
    for (int nt=0; nt<NT2; ++nt){
      short8 b = *(const short8*)(wp2 + (size_t)((nt*KC2+kc)*64 + lane)*8);
      acc2[nt] = __builtin_amdgcn_mfma_f32_16x16x32_bf16(a, b, acc2[nt], 0, 0, 0);
    }
  }
  #pragma unroll
  for (int nt=0; nt<NT2; ++nt){
    int c = nt*16 + m16;
    float bias = b2[c];
    #pragma unroll
    for (int r=0;r<4;++r){
      float v = fmaxf(acc2[nt][r] + bias, 0.f);
      int mm = quad*4 + r;
      int row = row0 + mm;
      if constexpr (!LAST){
        if (row < n) xout[(size_t)row*M2 + c] = f2bf(v);
      } else {
        if (row < n) embp[(size_t)row*64 + c] = v;                // f32 emb
        sX3[(w*8 + (c>>3))*136 + mm*8 + (c&7)] = (short)f2bf(v);
      }
    }
  }

  if constexpr (LAST){
    __syncthreads();
    floatx4 accf = (floatx4){0.f,0.f,0.f,0.f};
    #pragma unroll
    for (int kc=0; kc<2; ++kc){
      short8 a = *(const short8*)&sX3[(w*8 + kc*4 + quad)*136 + m16*8];
      short8 b = *(const short8*)(wpfc + (size_t)(kc*64 + lane)*8);
      accf = __builtin_amdgcn_mfma_f32_16x16x32_bf16(a, b, accf, 0, 0, 0);
    }
    if (m16 < 8){
      float bias = bfc[m16];
      #pragma unroll
      for (int r=0;r<4;++r){
        int row = row0 + quad*4 + r;
        if (row < n) outp[(size_t)row*8 + m16] = accf[r] + bias;  // f32 out
      }
    }
  }
}

// ---------------- launcher ----------------

extern "C" void kernel_launch(void* const* d_in, const int* in_sizes, int n_in,
                              void* d_out, int out_size, void* d_ws, size_t ws_size,
                              hipStream_t stream)
{
  const int N = in_sizes[0] / 64;
  const int E = in_sizes[1] / 2;
  const int NB = (N + 511) / 512;
  const float*        x    = (const float*)d_in[0];
  const unsigned int* ew   = (const unsigned int*)d_in[1];
  const float* eps1 = (const float*)d_in[2];
  const float* eps2 = (const float*)d_in[3];
  const float* eps3 = (const float*)d_in[4];
  const float* W1a  = (const float*)d_in[5];
  const float* b1a  = (const float*)d_in[6];
  const float* W1b  = (const float*)d_in[7];
  const float* b1b  = (const float*)d_in[8];
  const float* W2a  = (const float*)d_in[9];
  const float* b2a  = (const float*)d_in[10];
  const float* W2b  = (const float*)d_in[11];
  const float* b2b  = (const float*)d_in[12];
  const float* W3a  = (const float*)d_in[13];
  const float* b3a  = (const float*)d_in[14];
  const float* W3b  = (const float*)d_in[15];
  const float* b3b  = (const float*)d_in[16];
  const float* Wfc  = (const float*)d_in[17];
  const float* bfc  = (const float*)d_in[18];

  float* outp = (float*)d_out;                 // f32 output (verified round 6)
  float* emb  = outp + (size_t)N*8;

  const int Npad = ((N + 63)/64)*64;

  char* ws = (char*)d_ws;
  size_t o = 0;
  auto alloc = [&](size_t bytes)->char* {
    char* p = ws + o;
    o = (o + bytes + 255) & ~(size_t)255;
    return p;
  };
  int*      ghist = (int*)alloc(256*4);
  int*      bbase = (int*)alloc(257*4);
  int*      gcur  = (int*)alloc(256*4);
  int*      offs  = (int*)alloc((size_t)(N+1)*4);
  int2*     pairs = (int2*)alloc((size_t)E*8);
  int*      csr   = (int*)alloc((size_t)E*4);
  ushort_t* wperm = (ushort_t*)alloc(70656ull*2);
  ushort_t* xb    = (ushort_t*)alloc((size_t)Npad*64*2);    // bf16 copy of x
  ushort_t* hbuf  = (ushort_t*)alloc((size_t)Npad*128*2);   // gather output (bf16)
  ushort_t* x1    = (ushort_t*)alloc((size_t)Npad*128*2);   // layer outputs (bf16)

  hipMemsetAsync(ghist, 0, 256*4, stream);
  const int nbB   = (E + 4095)/4096;
  const int tobfB = (N*32 + 255)/256;
  const int permB = 70656/256;
  k_prep<<<nbB + tobfB + permB, 256, 0, stream>>>(ew, ghist, E, N, nbB,
                                                  (const float2*)x, (unsigned int*)xb, N*32, tobfB,
                                                  W1a, W1b, W2a, W2b, W3a, W3b, Wfc, wperm);
  k_bscan<<<1, 256, 0, stream>>>(ghist, bbase, gcur, NB);
  k_bin<<<nbB, 256, 0, stream>>>(ew, gcur, pairs, E, N, NB);
  k_bcsr<<<NB, 256, 0, stream>>>(pairs, bbase, offs, csr, N, NB);

  // layer 1 (64 -> 128): gather F=64 (2 nodes/wave)
  k_gatherx<64><<<(((N+1)/2)+3)/4, 256, 0, stream>>>((const uint2*)xb, offs, csr, eps1,
                                                     (uint2*)hbuf, N);
  k_mlp<64,128,128,false><<<Npad/64, 256, 0, stream>>>(hbuf, wperm+0, b1a, wperm+8192, b1b,
                                                       x1, nullptr, nullptr, nullptr, nullptr, N);
  // layer 2 (128 -> 128)
  k_gatherx<128><<<(N+3)/4, 256, 0, stream>>>((const uint2*)x1, offs, csr, eps2,
                                              (uint2*)hbuf, N);
  k_mlp<128,128,128,false><<<Npad/64, 256, 0, stream>>>(hbuf, wperm+24576, b2a, wperm+40960, b2b,
                                                        x1, nullptr, nullptr, nullptr, nullptr, N);
  // layer 3 (128 -> 64) + FC (64 -> 8)
  k_gatherx<128><<<(N+3)/4, 256, 0, stream>>>((const uint2*)x1, offs, csr, eps3,
                                              (uint2*)hbuf, N);
  k_mlp<128,64,64,true><<<Npad/64, 256, 0, stream>>>(hbuf, wperm+57344, b3a, wperm+65536, b3b,
                                                     nullptr, emb, wperm+69632, bfc, outp, N);
}